// Round 2
// baseline (297.560 us; speedup 1.0000x reference)
//
#include <hip/hip_runtime.h>
#include <hip/hip_bf16.h>
#include <stdint.h>

// ---------------- common types / helpers ----------------
typedef __attribute__((ext_vector_type(8))) short  bf16x8;   // 8 bf16 in 4 VGPRs
typedef __attribute__((ext_vector_type(4))) float  f32x4;
typedef __attribute__((ext_vector_type(4))) unsigned int u32x4;
typedef __attribute__((ext_vector_type(2))) unsigned int u32x2;

#define LOG2E 1.4426950408889634f

__device__ __forceinline__ unsigned short f2bf(float f) {
  unsigned int u = __builtin_bit_cast(unsigned int, f);
  u += 0x7fffu + ((u >> 16) & 1u);          // round-to-nearest-even
  return (unsigned short)(u >> 16);
}

// packed 2xfp32 -> 2xbf16 (v_cvt_pk_bf16_f32 on gfx950), returned as u32
__device__ __forceinline__ unsigned int pk2(float a, float b) {
  __hip_bfloat162 h = __float22bfloat162_rn(make_float2(a, b));
  unsigned int u;
  __builtin_memcpy(&u, &h, 4);
  return u;
}

// async global->LDS, 16B per lane. LDS dest = wave-uniform base + lane*16.
__device__ __forceinline__ void async16(const void* g, void* l) {
  __builtin_amdgcn_global_load_lds(
      (const __attribute__((address_space(1))) unsigned int*)g,
      (__attribute__((address_space(3))) unsigned int*)l,
      16, 0, 0);
}

// ---------------- cast all fp32 inputs -> bf16 in one launch ----------------
// x: 2,097,152 float4; weights: 4 x 262,144 float4. Grid 12288 x 256.
__global__ __launch_bounds__(256) void cast_all(
    const float* __restrict__ x,
    const float* __restrict__ Wq, const float* __restrict__ Wk,
    const float* __restrict__ Wv, const float* __restrict__ Wo,
    unsigned short* __restrict__ xb, unsigned short* __restrict__ wqkv,
    unsigned short* __restrict__ wo) {
  int i = blockIdx.x * 256 + threadIdx.x;
  const float* src;
  unsigned short* dst;
  int off;
  if (i < 2097152) {
    src = x; dst = xb; off = i;
  } else {
    int j = i - 2097152;
    int seg = j >> 18; off = j & 262143;
    src = (seg == 0) ? Wq : (seg == 1) ? Wk : (seg == 2) ? Wv : Wo;
    dst = (seg < 3) ? (wqkv + (size_t)seg * 1048576) : wo;
  }
  float4 f = ((const float4*)src)[off];
  uint2 o;
  o.x = pk2(f.x, f.y);
  o.y = pk2(f.z, f.w);
  ((uint2*)dst)[off] = o;
}

// ---------------- QKV GEMM: C[8192,3072] = x_bf16 @ Wqkv^T + bias ----------------
// XCD-swizzled 1D grid (1536): each XCD owns 3 n-tiles -> its 0.75 MB B strip
// stays L2-resident across all 64 m-tiles. Epilogue stages each wave's 64x64 C
// quadrant in private LDS (stride 72), then coalesced 16B stores.
// Q is scaled by 0.125*log2(e): attn then uses exp2() directly.
__global__ __launch_bounds__(256) void gemm_qkv(
    const unsigned short* __restrict__ xb, const unsigned short* __restrict__ wqkv,
    const float* __restrict__ bq, const float* __restrict__ bk, const float* __restrict__ bv,
    unsigned short* __restrict__ qb, unsigned short* __restrict__ kb,
    unsigned short* __restrict__ vb) {
  __shared__ __align__(16) unsigned short As[128 * 32];
  __shared__ __align__(16) unsigned short Bs[128 * 32];
  __shared__ __align__(16) unsigned short epi[4][64 * 72];   // 36 KB, wave-private
  const int bid = blockIdx.x;
  const int xcd = bid & 7, idx = bid >> 3;       // bid%8 ~ XCD round-robin heuristic
  const int nt = xcd * 3 + (idx % 3);            // 24 n-tiles: 3 per XCD
  const int mt = idx / 3;                        // 64 m-tiles
  const int m0 = mt * 128, n0 = nt * 128;
  const int tid = threadIdx.x;
  const int wv = tid >> 6, lane = tid & 63, qq = lane >> 4, ln = lane & 15;
  const int wm = wv & 1, wn = wv >> 1;
  const int K = 1024;

  f32x4 acc[4][4];
#pragma unroll
  for (int i = 0; i < 4; ++i)
#pragma unroll
    for (int j = 0; j < 4; ++j) acc[i][j] = f32x4{0.f, 0.f, 0.f, 0.f};

  for (int k0 = 0; k0 < K; k0 += 32) {
#pragma unroll
    for (int i = 0; i < 2; ++i) {
      int cc = wv * 2 + i;
      int jp = cc * 64 + lane;
      int row = jp >> 2, cp = jp & 3;
      int c = cp ^ ((row >> 1) & 3);
      async16(xb   + (size_t)(m0 + row) * K + k0 + c * 8, As + cc * 512);
      async16(wqkv + (size_t)(n0 + row) * K + k0 + c * 8, Bs + cc * 512);
    }
    __syncthreads();
    bf16x8 af[4], bf[4];
#pragma unroll
    for (int i = 0; i < 4; ++i) {
      int row = wm * 64 + i * 16 + ln;
      af[i] = *(const bf16x8*)(As + row * 32 + (qq ^ ((row >> 1) & 3)) * 8);
    }
#pragma unroll
    for (int j = 0; j < 4; ++j) {
      int row = wn * 64 + j * 16 + ln;
      bf[j] = *(const bf16x8*)(Bs + row * 32 + (qq ^ ((row >> 1) & 3)) * 8);
    }
#pragma unroll
    for (int i = 0; i < 4; ++i)
#pragma unroll
      for (int j = 0; j < 4; ++j)
        acc[i][j] = __builtin_amdgcn_mfma_f32_16x16x32_bf16(af[i], bf[j], acc[i][j], 0, 0, 0);
    __syncthreads();
  }

  const int nblk = n0 >> 10;                           // 0=Q 1=K 2=V (block-uniform)
  const float* bias = (nblk == 0) ? bq : (nblk == 1) ? bk : bv;
  // Q: fold 1/sqrt(64) AND log2(e) so attention can use exp2 directly
  const float scale = (nblk == 0) ? (0.125f * LOG2E) : 1.0f;
  unsigned short* buf = epi[wv];
  const int ncol0 = (n0 & 1023) + wn * 64;             // multiple of 64
  const int head  = ncol0 >> 6;
  const int mbase = m0 + wm * 64;
  const int b     = mbase >> 11, sbase = mbase & 2047;
  unsigned short* dst = (nblk == 0) ? qb : (nblk == 1) ? kb : vb;

  if (nblk != 2) {
    // ---- Q/K: LDS layout [m(s)][n(d)], stride 72 elems ----
#pragma unroll
    for (int j = 0; j < 4; ++j) {
      float bs = bias[ncol0 + j * 16 + ln] * scale;
#pragma unroll
      for (int i = 0; i < 4; ++i)
#pragma unroll
        for (int r = 0; r < 4; ++r)
          buf[(i * 16 + qq * 4 + r) * 72 + j * 16 + ln] = f2bf(acc[i][j][r] * scale + bs);
    }
    unsigned short* gout = dst + (((size_t)(b * 16 + head)) * 2048 + sbase) * 64;
#pragma unroll
    for (int h = 0; h < 2; ++h)
#pragma unroll
      for (int p = 0; p < 4; ++p) {
        int rr = (lane >> 2) + p * 16;
        int c4 = lane & 3;
        ulonglong2 v = *(const ulonglong2*)(buf + rr * 72 + h * 32 + c4 * 8);
        *(ulonglong2*)(gout + (size_t)rr * 64 + h * 32 + c4 * 8) = v;
      }
  } else {
    // ---- V: LDS layout [n(d)][m(s)], stride 72 elems; packed b64 writes ----
#pragma unroll
    for (int j = 0; j < 4; ++j) {
      float bs = bias[ncol0 + j * 16 + ln];
#pragma unroll
      for (int i = 0; i < 4; ++i) {
        uint2 pk;
        pk.x = pk2(acc[i][j][0] + bs, acc[i][j][1] + bs);
        pk.y = pk2(acc[i][j][2] + bs, acc[i][j][3] + bs);
        *(uint2*)(buf + (j * 16 + ln) * 72 + i * 16 + qq * 4) = pk;
      }
    }
    unsigned short* gout = dst + ((size_t)(b * 16 + head)) * 64 * 2048 + sbase;
#pragma unroll
    for (int p = 0; p < 8; ++p) {
      int dr = (lane >> 3) + p * 8;
      int c8 = lane & 7;
      ulonglong2 v = *(const ulonglong2*)(buf + dr * 72 + c8 * 8);
      *(ulonglong2*)(gout + (size_t)dr * 2048 + c8 * 8) = v;
    }
  }
}

// ---------------- flash attention: 1 barrier/iter, in-register P ----------
// K and V^T both double-buffered (32 KB LDS). Per tile: stage(t+1) -> QK^T ->
// softmax entirely in registers (cvt_pk + permlane32/16_swap converts the
// QK C-layout to the PV B-fragment layout; no P LDS roundtrip) -> PV ->
// vmcnt(0) (covered by compute) -> ONE barrier. No internal barriers: waves
// drift so one wave's softmax (VALU/trans) overlaps another's MFMA phases.
__global__ __launch_bounds__(256, 4) void attn_kernel(
    const unsigned short* __restrict__ qb, const unsigned short* __restrict__ kb,
    const unsigned short* __restrict__ vb, unsigned short* __restrict__ ctx) {
  __shared__ __align__(16) unsigned short k_sh[2][64 * 64];   // [kpos][d] dbuf 16 KB
  __shared__ __align__(16) unsigned short vT_sh[2][64 * 64];  // [d][kpos] dbuf 16 KB
  const int bid = blockIdx.x;
  const int xcd = bid & 7, idx = bid >> 3;       // 128 blocks per XCD
  const int bh = xcd * 8 + (idx >> 4);           // 8 heads per XCD
  const int q0 = (idx & 15) * 128;
  const int tid = threadIdx.x;
  const int wv = tid >> 6, lane = tid & 63, qq = lane >> 4, ln = lane & 15;

  // Q as B-fragments: B[k=d][n=qrow], lane n=ln, k=qq*8+j (+32 per kq)
  bf16x8 qf[2][2];
  {
    const unsigned short* qbase = qb + ((size_t)bh * 2048 + q0 + wv * 32) * 64;
#pragma unroll
    for (int rb = 0; rb < 2; ++rb)
#pragma unroll
      for (int kq = 0; kq < 2; ++kq)
        qf[rb][kq] = *(const bf16x8*)(qbase + (rb * 16 + ln) * 64 + kq * 32 + qq * 8);
  }

  // O^T accumulators: D[m=d (nt tiles)][n=qrow (rb tiles)]; lane: qrow=ln, d=qq*4+r
  f32x4 o_acc[2][4];
  float l_i[2] = {0.f, 0.f};                       // per-lane partial row sums
#pragma unroll
  for (int rb = 0; rb < 2; ++rb)
#pragma unroll
    for (int nt = 0; nt < 4; ++nt) o_acc[rb][nt] = f32x4{0.f, 0.f, 0.f, 0.f};

  const unsigned short* kgbase = kb + (size_t)bh * 2048 * 64;
  const unsigned short* vgbase = vb + (size_t)bh * 64 * 2048;
  const int cc0 = wv * 2;                          // this wave's 2 staging chunks

  // stage one 64x64 K tile + one 64x64 V^T tile (4 global_load_lds per wave)
  auto stageKV = [&](int kt, int buf) {
#pragma unroll
    for (int i = 0; i < 2; ++i) {
      int jp = (cc0 + i) * 64 + lane;              // 0..511
      int row = jp >> 3, c = (jp & 7) ^ (row & 7); // pre-swizzled global source
      async16(kgbase + (size_t)(kt * 64 + row) * 64 + c * 8, k_sh[buf] + (cc0 + i) * 512);
      async16(vgbase + (size_t)row * 2048 + kt * 64 + c * 8, vT_sh[buf] + (cc0 + i) * 512);
    }
  };

  stageKV(0, 0);
  asm volatile("s_waitcnt vmcnt(0)" ::: "memory");
  __builtin_amdgcn_s_barrier();

  for (int kt = 0; kt < 32; ++kt) {
    const int cur = kt & 1;
    const unsigned short* kcur = k_sh[cur];
    const unsigned short* vcur = vT_sh[cur];
    // prefetch next tile into the buffer all waves finished before last barrier
    if (kt < 31) stageKV(kt + 1, cur ^ 1);

    // ---- S^T = K @ Q^T : K-fragments loaded once, both rb accumulated ----
    f32x4 s_acc[2][4];
#pragma unroll
    for (int rb = 0; rb < 2; ++rb)
#pragma unroll
      for (int ct = 0; ct < 4; ++ct) s_acc[rb][ct] = f32x4{0.f, 0.f, 0.f, 0.f};
    __builtin_amdgcn_s_setprio(1);
#pragma unroll
    for (int ct = 0; ct < 4; ++ct) {
      int row = ct * 16 + ln;
      bf16x8 kf0 = *(const bf16x8*)(kcur + row * 64 + ((0 + qq) ^ (row & 7)) * 8);
      bf16x8 kf1 = *(const bf16x8*)(kcur + row * 64 + ((4 + qq) ^ (row & 7)) * 8);
#pragma unroll
      for (int rb = 0; rb < 2; ++rb) {
        s_acc[rb][ct] = __builtin_amdgcn_mfma_f32_16x16x32_bf16(kf0, qf[rb][0], s_acc[rb][ct], 0, 0, 0);
        s_acc[rb][ct] = __builtin_amdgcn_mfma_f32_16x16x32_bf16(kf1, qf[rb][1], s_acc[rb][ct], 0, 0, 0);
      }
    }
    __builtin_amdgcn_s_setprio(0);

    // ---- softmax fully in registers ----
    // s_acc layout: lane(qq,ln) reg r of block ct = P[kpos=ct*16+qq*4+r][qrow=ln].
    // PV B-frag needs: lane(qq,ln) word j2 of half kk = P[kpos=kk*32+qq*8+2*j2+{0,1}][ln].
    // With A=W[2kk][w], B=W[2kk+1][w]:
    //   x1 = permlane32_swap(A,B)  -> x=[A0,A1,B0,B1] y=[A2,A3,B2,B3]  (by 16-lane quad)
    //   x2 = permlane16_swap(x,y)  -> x=[A0,A2,B0,B2]=word w, y=[A1,A3,B1,B3]=word 2+w
    bf16x8 pf[2][2];
#pragma unroll
    for (int rb = 0; rb < 2; ++rb) {
      unsigned int W[4][2];
      float sum = 0.f;
#pragma unroll
      for (int ct = 0; ct < 4; ++ct) {
        float p0 = __builtin_amdgcn_exp2f(s_acc[rb][ct][0]);
        float p1 = __builtin_amdgcn_exp2f(s_acc[rb][ct][1]);
        float p2 = __builtin_amdgcn_exp2f(s_acc[rb][ct][2]);
        float p3 = __builtin_amdgcn_exp2f(s_acc[rb][ct][3]);
        sum += (p0 + p1) + (p2 + p3);
        W[ct][0] = pk2(p0, p1);
        W[ct][1] = pk2(p2, p3);
      }
      l_i[rb] += sum;
#pragma unroll
      for (int kk = 0; kk < 2; ++kk) {
        u32x2 a1 = __builtin_amdgcn_permlane32_swap(W[2 * kk][0], W[2 * kk + 1][0], false, false);
        u32x2 a2 = __builtin_amdgcn_permlane16_swap(a1.x, a1.y, false, false);
        u32x2 b1 = __builtin_amdgcn_permlane32_swap(W[2 * kk][1], W[2 * kk + 1][1], false, false);
        u32x2 b2 = __builtin_amdgcn_permlane16_swap(b1.x, b1.y, false, false);
        u32x4 pw = {a2.x, b2.x, a2.y, b2.y};     // words j2 = 0,1,2,3
        pf[rb][kk] = __builtin_bit_cast(bf16x8, pw);
      }
    }

    // ---- O^T += V^T @ P^T : A=V^T (m=d), B=P in registers ----
#pragma unroll
    for (int kk = 0; kk < 2; ++kk) {
      bf16x8 vf[4];
#pragma unroll
      for (int nt = 0; nt < 4; ++nt) {
        int row = nt * 16 + ln;
        vf[nt] = *(const bf16x8*)(vcur + row * 64 + ((kk * 4 + qq) ^ (row & 7)) * 8);
      }
      __builtin_amdgcn_s_setprio(1);
#pragma unroll
      for (int rb = 0; rb < 2; ++rb)
#pragma unroll
        for (int nt = 0; nt < 4; ++nt)
          o_acc[rb][nt] = __builtin_amdgcn_mfma_f32_16x16x32_bf16(vf[nt], pf[rb][kk], o_acc[rb][nt], 0, 0, 0);
      __builtin_amdgcn_s_setprio(0);
    }

    // own stage(t+1) loads landed (covered by the whole compute above);
    // barrier then makes them visible to all waves AND signals this buffer free
    if (kt < 31) asm volatile("s_waitcnt vmcnt(0)" ::: "memory");
    __builtin_amdgcn_s_barrier();
  }

  // finalize row sums (cross-quad), normalize, transpose via reused k_sh LDS
  unsigned short* ep = (unsigned short*)k_sh;      // 128 rows x 64 cols, swizzled
#pragma unroll
  for (int rb = 0; rb < 2; ++rb) {
    l_i[rb] += __shfl_xor(l_i[rb], 16);
    l_i[rb] += __shfl_xor(l_i[rb], 32);
    float inv = 1.0f / l_i[rb];
    int row = wv * 32 + rb * 16 + ln;
    int rs = row & 7;
#pragma unroll
    for (int nt = 0; nt < 4; ++nt) {
      uint2 pk;
      pk.x = pk2(o_acc[rb][nt][0] * inv, o_acc[rb][nt][1] * inv);
      pk.y = pk2(o_acc[rb][nt][2] * inv, o_acc[rb][nt][3] * inv);
      *(uint2*)(ep + row * 64 + (((nt * 2 + (qq >> 1)) ^ rs) << 3) + ((qq & 1) << 2)) = pk;
    }
  }
  // transpose read is same-wave as the writes (tid>>1 stays in this wave's
  // 32-row slice): in-order LDS pipe, no barrier needed.
  {
    const int b = bh >> 4, h = bh & 15;
    int r = tid >> 1, half = tid & 1;
    int rs = r & 7;
    int s = q0 + r;
    size_t gbase = ((size_t)(b * 2048 + s)) * 1024 + h * 64 + half * 32;
    const unsigned short* lsrc = ep + r * 64;
#pragma unroll
    for (int j = 0; j < 4; ++j)
      ((ulonglong2*)(ctx + gbase + j * 8))[0] =
          *(const ulonglong2*)(lsrc + (((half * 4 + j) ^ rs) << 3));
  }
}

// ---------------- output GEMM: out[8192,1024] = ctx @ Wo^T + bo (fp32 out) ----------------
// XCD-swizzled 1D grid (512): 1 n-tile per XCD -> 0.25 MB B strip L2-resident.
// Only 2 blocks/CU -> little TLP: double-buffer staging with counted vmcnt
// (raw s_barrier, never drain to 0 in-loop) to hide load latency intra-block.
__global__ __launch_bounds__(256) void gemm_out(
    const unsigned short* __restrict__ ctx, const unsigned short* __restrict__ wo,
    const float* __restrict__ bo, float* __restrict__ out) {
  __shared__ __align__(16) unsigned short As[2][128 * 32];   // 16 KB
  __shared__ __align__(16) unsigned short Bs[2][128 * 32];   // 16 KB
  const int bid = blockIdx.x;
  const int n0 = (bid & 7) * 128;
  const int m0 = (bid >> 3) * 128;
  const int tid = threadIdx.x;
  const int wv = tid >> 6, lane = tid & 63, qq = lane >> 4, ln = lane & 15;
  const int wm = wv & 1, wn = wv >> 1;
  const int K = 1024;

  f32x4 acc[4][4];
#pragma unroll
  for (int i = 0; i < 4; ++i)
#pragma unroll
    for (int j = 0; j < 4; ++j) acc[i][j] = f32x4{0.f, 0.f, 0.f, 0.f};

  auto stage = [&](int t, int buf) {               // 4 loads per wave
#pragma unroll
    for (int i = 0; i < 2; ++i) {
      int cc = wv * 2 + i;
      int jp = cc * 64 + lane;
      int row = jp >> 2, cp = jp & 3;
      int c = cp ^ ((row >> 1) & 3);
      async16(ctx + (size_t)(m0 + row) * K + t * 32 + c * 8, As[buf] + cc * 512);
      async16(wo  + (size_t)(n0 + row) * K + t * 32 + c * 8, Bs[buf] + cc * 512);
    }
  };

  stage(0, 0);
  for (int t = 0; t < 32; ++t) {
    const int cur = t & 1;
    if (t < 31) {
      stage(t + 1, cur ^ 1);
      // outstanding: stage(t)[4] + stage(t+1)[4] -> retire stage(t) only
      asm volatile("s_waitcnt vmcnt(4)" ::: "memory");
    } else {
      asm volatile("s_waitcnt vmcnt(0)" ::: "memory");
    }
    __builtin_amdgcn_s_barrier();                  // buf[cur] visible from all waves

    bf16x8 af[4], bf[4];
#pragma unroll
    for (int i = 0; i < 4; ++i) {
      int row = wm * 64 + i * 16 + ln;
      af[i] = *(const bf16x8*)(As[cur] + row * 32 + (qq ^ ((row >> 1) & 3)) * 8);
    }
#pragma unroll
    for (int j = 0; j < 4; ++j) {
      int row = wn * 64 + j * 16 + ln;
      bf[j] = *(const bf16x8*)(Bs[cur] + row * 32 + (qq ^ ((row >> 1) & 3)) * 8);
    }
#pragma unroll
    for (int i = 0; i < 4; ++i)
#pragma unroll
      for (int j = 0; j < 4; ++j)
        acc[i][j] = __builtin_amdgcn_mfma_f32_16x16x32_bf16(af[i], bf[j], acc[i][j], 0, 0, 0);
    __builtin_amdgcn_s_barrier();                  // done reading buf[cur]
  }

#pragma unroll
  for (int j = 0; j < 4; ++j) {
    int n = n0 + wn * 64 + j * 16 + ln;
    float bsv = bo[n];
#pragma unroll
    for (int i = 0; i < 4; ++i) {
#pragma unroll
      for (int r = 0; r < 4; ++r) {
        int m = m0 + wm * 64 + i * 16 + qq * 4 + r;
        out[(size_t)m * 1024 + n] = acc[i][j][r] + bsv;
      }
    }
  }
}

// ---------------- launch ----------------
extern "C" void kernel_launch(void* const* d_in, const int* in_sizes, int n_in,
                              void* d_out, int out_size, void* d_ws, size_t ws_size,
                              hipStream_t stream) {
  const float* x  = (const float*)d_in[0];
  const float* Wq = (const float*)d_in[1];
  const float* bq = (const float*)d_in[2];
  const float* Wk = (const float*)d_in[3];
  const float* bk = (const float*)d_in[4];
  const float* Wv = (const float*)d_in[5];
  const float* bv = (const float*)d_in[6];
  const float* Wo = (const float*)d_in[7];
  const float* bo = (const float*)d_in[8];
  float* out = (float*)d_out;

  char* ws = (char*)d_ws;
  unsigned short* xb   = (unsigned short*)(ws);                      // 16M
  unsigned short* ctxb = (unsigned short*)(ws);                      // reuse
  unsigned short* qb   = (unsigned short*)(ws + ((size_t)16 << 20)); // 16M
  unsigned short* kbuf = (unsigned short*)(ws + ((size_t)32 << 20)); // 16M
  unsigned short* vbuf = (unsigned short*)(ws + ((size_t)48 << 20)); // 16M
  unsigned short* wqkv = (unsigned short*)(ws + ((size_t)64 << 20)); // 6M
  unsigned short* wo   = (unsigned short*)(ws + ((size_t)70 << 20)); // 2M

  cast_all<<<12288, 256, 0, stream>>>(x, Wq, Wk, Wv, Wo, xb, wqkv, wo);

  gemm_qkv<<<1536, 256, 0, stream>>>(xb, wqkv, bq, bk, bv, qb, kbuf, vbuf);
  attn_kernel<<<1024, 256, 0, stream>>>(qb, kbuf, vbuf, ctxb);
  gemm_out<<<512, 256, 0, stream>>>(ctxb, wo, bo, out);
}

// Round 5
// 287.229 us; speedup vs baseline: 1.0360x; 1.0360x over previous
//
#include <hip/hip_runtime.h>
#include <hip/hip_bf16.h>
#include <stdint.h>

// ---------------- common types / helpers ----------------
typedef __attribute__((ext_vector_type(8))) short  bf16x8;   // 8 bf16 in 4 VGPRs
typedef __attribute__((ext_vector_type(4))) float  f32x4;
typedef __attribute__((ext_vector_type(4))) unsigned int u32x4;
typedef __attribute__((ext_vector_type(2))) unsigned int u32x2;

#define LOG2E 1.4426950408889634f

__device__ __forceinline__ unsigned short f2bf(float f) {
  unsigned int u = __builtin_bit_cast(unsigned int, f);
  u += 0x7fffu + ((u >> 16) & 1u);          // round-to-nearest-even
  return (unsigned short)(u >> 16);
}

// packed 2xfp32 -> 2xbf16 (v_cvt_pk_bf16_f32 on gfx950), returned as u32
__device__ __forceinline__ unsigned int pk2(float a, float b) {
  __hip_bfloat162 h = __float22bfloat162_rn(make_float2(a, b));
  unsigned int u;
  __builtin_memcpy(&u, &h, 4);
  return u;
}

// async global->LDS, 16B per lane. LDS dest = wave-uniform base + lane*16.
__device__ __forceinline__ void async16(const void* g, void* l) {
  __builtin_amdgcn_global_load_lds(
      (const __attribute__((address_space(1))) unsigned int*)g,
      (__attribute__((address_space(3))) unsigned int*)l,
      16, 0, 0);
}

// ---------------- cast all fp32 inputs -> bf16 in one launch ----------------
// x: 2,097,152 float4; weights: 4 x 262,144 float4. Grid 12288 x 256.
__global__ __launch_bounds__(256) void cast_all(
    const float* __restrict__ x,
    const float* __restrict__ Wq, const float* __restrict__ Wk,
    const float* __restrict__ Wv, const float* __restrict__ Wo,
    unsigned short* __restrict__ xb, unsigned short* __restrict__ wqkv,
    unsigned short* __restrict__ wo) {
  int i = blockIdx.x * 256 + threadIdx.x;
  const float* src;
  unsigned short* dst;
  int off;
  if (i < 2097152) {
    src = x; dst = xb; off = i;
  } else {
    int j = i - 2097152;
    int seg = j >> 18; off = j & 262143;
    src = (seg == 0) ? Wq : (seg == 1) ? Wk : (seg == 2) ? Wv : Wo;
    dst = (seg < 3) ? (wqkv + (size_t)seg * 1048576) : wo;
  }
  float4 f = ((const float4*)src)[off];
  uint2 o;
  o.x = pk2(f.x, f.y);
  o.y = pk2(f.z, f.w);
  ((uint2*)dst)[off] = o;
}

// ---------------- QKV GEMM: C[8192,3072] = x_bf16 @ Wqkv^T + bias ----------------
// XCD-swizzled 1D grid (1536): each XCD owns 3 n-tiles -> its 0.75 MB B strip
// stays L2-resident across all 64 m-tiles. Epilogue stages each wave's 64x64 C
// quadrant in private LDS (stride 72), then coalesced 16B stores.
// Q is scaled by 0.125*log2(e): attn then uses exp2() directly.
__global__ __launch_bounds__(256) void gemm_qkv(
    const unsigned short* __restrict__ xb, const unsigned short* __restrict__ wqkv,
    const float* __restrict__ bq, const float* __restrict__ bk, const float* __restrict__ bv,
    unsigned short* __restrict__ qb, unsigned short* __restrict__ kb,
    unsigned short* __restrict__ vb) {
  __shared__ __align__(16) unsigned short As[128 * 32];
  __shared__ __align__(16) unsigned short Bs[128 * 32];
  __shared__ __align__(16) unsigned short epi[4][64 * 72];   // 36 KB, wave-private
  const int bid = blockIdx.x;
  const int xcd = bid & 7, idx = bid >> 3;       // bid%8 ~ XCD round-robin heuristic
  const int nt = xcd * 3 + (idx % 3);            // 24 n-tiles: 3 per XCD
  const int mt = idx / 3;                        // 64 m-tiles
  const int m0 = mt * 128, n0 = nt * 128;
  const int tid = threadIdx.x;
  const int wv = tid >> 6, lane = tid & 63, qq = lane >> 4, ln = lane & 15;
  const int wm = wv & 1, wn = wv >> 1;
  const int K = 1024;

  f32x4 acc[4][4];
#pragma unroll
  for (int i = 0; i < 4; ++i)
#pragma unroll
    for (int j = 0; j < 4; ++j) acc[i][j] = f32x4{0.f, 0.f, 0.f, 0.f};

  for (int k0 = 0; k0 < K; k0 += 32) {
#pragma unroll
    for (int i = 0; i < 2; ++i) {
      int cc = wv * 2 + i;
      int jp = cc * 64 + lane;
      int row = jp >> 2, cp = jp & 3;
      int c = cp ^ ((row >> 1) & 3);
      async16(xb   + (size_t)(m0 + row) * K + k0 + c * 8, As + cc * 512);
      async16(wqkv + (size_t)(n0 + row) * K + k0 + c * 8, Bs + cc * 512);
    }
    __syncthreads();
    bf16x8 af[4], bf[4];
#pragma unroll
    for (int i = 0; i < 4; ++i) {
      int row = wm * 64 + i * 16 + ln;
      af[i] = *(const bf16x8*)(As + row * 32 + (qq ^ ((row >> 1) & 3)) * 8);
    }
#pragma unroll
    for (int j = 0; j < 4; ++j) {
      int row = wn * 64 + j * 16 + ln;
      bf[j] = *(const bf16x8*)(Bs + row * 32 + (qq ^ ((row >> 1) & 3)) * 8);
    }
#pragma unroll
    for (int i = 0; i < 4; ++i)
#pragma unroll
      for (int j = 0; j < 4; ++j)
        acc[i][j] = __builtin_amdgcn_mfma_f32_16x16x32_bf16(af[i], bf[j], acc[i][j], 0, 0, 0);
    __syncthreads();
  }

  const int nblk = n0 >> 10;                           // 0=Q 1=K 2=V (block-uniform)
  const float* bias = (nblk == 0) ? bq : (nblk == 1) ? bk : bv;
  // Q: fold 1/sqrt(64) AND log2(e) so attention can use exp2 directly
  const float scale = (nblk == 0) ? (0.125f * LOG2E) : 1.0f;
  unsigned short* buf = epi[wv];
  const int ncol0 = (n0 & 1023) + wn * 64;             // multiple of 64
  const int head  = ncol0 >> 6;
  const int mbase = m0 + wm * 64;
  const int b     = mbase >> 11, sbase = mbase & 2047;
  unsigned short* dst = (nblk == 0) ? qb : (nblk == 1) ? kb : vb;

  if (nblk != 2) {
    // ---- Q/K: LDS layout [m(s)][n(d)], stride 72 elems ----
#pragma unroll
    for (int j = 0; j < 4; ++j) {
      float bs = bias[ncol0 + j * 16 + ln] * scale;
#pragma unroll
      for (int i = 0; i < 4; ++i)
#pragma unroll
        for (int r = 0; r < 4; ++r)
          buf[(i * 16 + qq * 4 + r) * 72 + j * 16 + ln] = f2bf(acc[i][j][r] * scale + bs);
    }
    unsigned short* gout = dst + (((size_t)(b * 16 + head)) * 2048 + sbase) * 64;
#pragma unroll
    for (int h = 0; h < 2; ++h)
#pragma unroll
      for (int p = 0; p < 4; ++p) {
        int rr = (lane >> 2) + p * 16;
        int c4 = lane & 3;
        ulonglong2 v = *(const ulonglong2*)(buf + rr * 72 + h * 32 + c4 * 8);
        *(ulonglong2*)(gout + (size_t)rr * 64 + h * 32 + c4 * 8) = v;
      }
  } else {
    // ---- V: LDS layout [n(d)][m(s)], stride 72 elems; packed b64 writes ----
#pragma unroll
    for (int j = 0; j < 4; ++j) {
      float bs = bias[ncol0 + j * 16 + ln];
#pragma unroll
      for (int i = 0; i < 4; ++i) {
        uint2 pk;
        pk.x = pk2(acc[i][j][0] + bs, acc[i][j][1] + bs);
        pk.y = pk2(acc[i][j][2] + bs, acc[i][j][3] + bs);
        *(uint2*)(buf + (j * 16 + ln) * 72 + i * 16 + qq * 4) = pk;
      }
    }
    unsigned short* gout = dst + ((size_t)(b * 16 + head)) * 64 * 2048 + sbase;
#pragma unroll
    for (int p = 0; p < 8; ++p) {
      int dr = (lane >> 3) + p * 8;
      int c8 = lane & 7;
      ulonglong2 v = *(const ulonglong2*)(buf + dr * 72 + c8 * 8);
      *(ulonglong2*)(gout + (size_t)dr * 2048 + c8 * 8) = v;
    }
  }
}

// ---------------- flash attention: LDS-traffic-first restructure ----------
// Round-2's VERIFIED sync structure (dbuf K+V, asm vmcnt fences, one raw
// barrier per tile) and VERIFIED per-row math (in-reg P via permlane, fp32
// denominator) -- only the wave->work mapping changes: 64 q-rows per wave
// (rb=4), 256 per block, grid 512. Rationale: all prior schedules pinned at
// ~94us because 16 ds_read_b128/tile/wave served only 32 MFMAs (LDS pipe
// ~98K cyc/CU > MFMA floor 79.5K). Same 16 reads now serve 64 MFMAs ->
// LDS read traffic halves to ~49K cyc/CU, below the MFMA floor.
// Rounds 3/4 lesson: plain __syncthreads with post-barrier global_load_lds
// raced (stale V => ~2e-3 errors); keep asm fences + raw barriers.
__global__ __launch_bounds__(256, 2) void attn_kernel(
    const unsigned short* __restrict__ qb, const unsigned short* __restrict__ kb,
    const unsigned short* __restrict__ vb, unsigned short* __restrict__ ctx) {
  // unified 32 KB LDS: [0..4095]=K buf0, [4096..8191]=K buf1,
  // [8192..12287]=V^T buf0, [12288..16383]=V^T buf1; epilogue reuses all.
  __shared__ __align__(16) unsigned short sh[16384];
  const int bid = blockIdx.x;
  const int xcd = bid & 7, idx = bid >> 3;       // 64 blocks per XCD
  const int bh = xcd * 8 + (idx >> 3);           // 8 heads per XCD (KV L2-resident)
  const int q0 = (idx & 7) * 256;                // 8 q-tiles of 256 rows
  const int tid = threadIdx.x;
  const int wv = tid >> 6, lane = tid & 63, qq = lane >> 4, ln = lane & 15;

  // Q as B-fragments: B[k=d][n=qrow]; 64 rows per wave (rb=0..3)
  bf16x8 qf[4][2];
  {
    const unsigned short* qbase = qb + ((size_t)bh * 2048 + q0 + wv * 64) * 64;
#pragma unroll
    for (int rb = 0; rb < 4; ++rb)
#pragma unroll
      for (int kq = 0; kq < 2; ++kq)
        qf[rb][kq] = *(const bf16x8*)(qbase + (rb * 16 + ln) * 64 + kq * 32 + qq * 8);
  }

  // O^T accumulators: D[m=d (nt)][n=qrow (rb)]; lane: qrow=ln, d=qq*4+r
  f32x4 o_acc[4][4];
  float l_i[4] = {0.f, 0.f, 0.f, 0.f};
#pragma unroll
  for (int rb = 0; rb < 4; ++rb)
#pragma unroll
    for (int nt = 0; nt < 4; ++nt) o_acc[rb][nt] = f32x4{0.f, 0.f, 0.f, 0.f};
  const f32x4 z4 = f32x4{0.f, 0.f, 0.f, 0.f};

  const unsigned short* kgbase = kb + (size_t)bh * 2048 * 64;
  const unsigned short* vgbase = vb + (size_t)bh * 64 * 2048;
  const int cc0 = wv * 2;                        // this wave's 2 staging chunks

  // stage one 64x64 K tile + one 64x64 V^T tile (4 global_load_lds per wave)
  auto stageKV = [&](int kt, int buf) {
#pragma unroll
    for (int i = 0; i < 2; ++i) {
      int jp = (cc0 + i) * 64 + lane;            // 0..511
      int row = jp >> 3, c = (jp & 7) ^ (row & 7); // pre-swizzled global source
      async16(kgbase + (size_t)(kt * 64 + row) * 64 + c * 8,
              sh + buf * 4096 + (cc0 + i) * 512);
      async16(vgbase + (size_t)row * 2048 + kt * 64 + c * 8,
              sh + 8192 + buf * 4096 + (cc0 + i) * 512);
    }
  };

  stageKV(0, 0);
  asm volatile("s_waitcnt vmcnt(0)" ::: "memory");
  __builtin_amdgcn_s_barrier();

  for (int kt = 0; kt < 32; ++kt) {
    const int cur = kt & 1;
    const unsigned short* kcur = sh + cur * 4096;
    const unsigned short* vcur = sh + 8192 + cur * 4096;
    // prefetch next tile into the buffer all waves finished before last barrier
    if (kt < 31) stageKV(kt + 1, cur ^ 1);

    // ---- K-fragments loaded ONCE, reused across 4 rb (the LDS-traffic fix) ----
    bf16x8 kf[4][2];
#pragma unroll
    for (int ct = 0; ct < 4; ++ct) {
      int row = ct * 16 + ln;
      kf[ct][0] = *(const bf16x8*)(kcur + row * 64 + ((0 + qq) ^ (row & 7)) * 8);
      kf[ct][1] = *(const bf16x8*)(kcur + row * 64 + ((4 + qq) ^ (row & 7)) * 8);
    }

    // ---- per rb: QK^T then in-register softmax (verified r1-r2 math) ----
    bf16x8 pf[4][2];
#pragma unroll
    for (int rb = 0; rb < 4; ++rb) {
      f32x4 s_acc[4];
      __builtin_amdgcn_s_setprio(1);
#pragma unroll
      for (int ct = 0; ct < 4; ++ct) {
        s_acc[ct] = __builtin_amdgcn_mfma_f32_16x16x32_bf16(kf[ct][0], qf[rb][0], z4, 0, 0, 0);
        s_acc[ct] = __builtin_amdgcn_mfma_f32_16x16x32_bf16(kf[ct][1], qf[rb][1], s_acc[ct], 0, 0, 0);
      }
      __builtin_amdgcn_s_setprio(0);
      // s_acc: lane(qq,ln) reg r of ct = P[kpos=ct*16+qq*4+r][qrow]
      unsigned int W[4][2];
#pragma unroll
      for (int ct = 0; ct < 4; ++ct) {
        float p0 = __builtin_amdgcn_exp2f(s_acc[ct][0]);
        float p1 = __builtin_amdgcn_exp2f(s_acc[ct][1]);
        float p2 = __builtin_amdgcn_exp2f(s_acc[ct][2]);
        float p3 = __builtin_amdgcn_exp2f(s_acc[ct][3]);
        l_i[rb] += (p0 + p1) + (p2 + p3);        // fp32 denominator (r4 lesson)
        W[ct][0] = pk2(p0, p1);
        W[ct][1] = pk2(p2, p3);
      }
      // permlane32_swap then permlane16_swap: QK C-layout -> PV B-fragment
#pragma unroll
      for (int kk = 0; kk < 2; ++kk) {
        u32x2 a1 = __builtin_amdgcn_permlane32_swap(W[2 * kk][0], W[2 * kk + 1][0], false, false);
        u32x2 a2 = __builtin_amdgcn_permlane16_swap(a1.x, a1.y, false, false);
        u32x2 b1 = __builtin_amdgcn_permlane32_swap(W[2 * kk][1], W[2 * kk + 1][1], false, false);
        u32x2 b2 = __builtin_amdgcn_permlane16_swap(b1.x, b1.y, false, false);
        u32x4 pw = {a2.x, b2.x, a2.y, b2.y};
        pf[rb][kk] = __builtin_bit_cast(bf16x8, pw);
      }
    }

    // ---- O^T += V^T @ P^T: V-fragments loaded once, reused across 4 rb ----
#pragma unroll
    for (int kk = 0; kk < 2; ++kk) {
      bf16x8 vf[4];
#pragma unroll
      for (int nt = 0; nt < 4; ++nt) {
        int row = nt * 16 + ln;
        vf[nt] = *(const bf16x8*)(vcur + row * 64 + ((kk * 4 + qq) ^ (row & 7)) * 8);
      }
      __builtin_amdgcn_s_setprio(1);
#pragma unroll
      for (int rb = 0; rb < 4; ++rb)
#pragma unroll
        for (int nt = 0; nt < 4; ++nt)
          o_acc[rb][nt] = __builtin_amdgcn_mfma_f32_16x16x32_bf16(vf[nt], pf[rb][kk], o_acc[rb][nt], 0, 0, 0);
      __builtin_amdgcn_s_setprio(0);
    }

    // own stage(t+1) loads landed (covered by compute); barrier publishes them
    if (kt < 31) asm volatile("s_waitcnt vmcnt(0)" ::: "memory");
    __builtin_amdgcn_s_barrier();
  }

  // finalize row sums (cross-quad), normalize, transpose via reused sh (32 KB)
  unsigned short* ep = sh;                       // 256 rows x 64 cols, swizzled
#pragma unroll
  for (int rb = 0; rb < 4; ++rb) {
    l_i[rb] += __shfl_xor(l_i[rb], 16);
    l_i[rb] += __shfl_xor(l_i[rb], 32);
    float inv = 1.0f / l_i[rb];
    int row = wv * 64 + rb * 16 + ln;
    int rs = row & 7;
#pragma unroll
    for (int nt = 0; nt < 4; ++nt) {
      uint2 pk;
      pk.x = pk2(o_acc[rb][nt][0] * inv, o_acc[rb][nt][1] * inv);
      pk.y = pk2(o_acc[rb][nt][2] * inv, o_acc[rb][nt][3] * inv);
      *(uint2*)(ep + row * 64 + (((nt * 2 + (qq >> 1)) ^ rs) << 3) + ((qq & 1) << 2)) = pk;
    }
  }
  // same-wave transposed read: thread tid reads row tid (rows [wv*64,wv*64+63]
  // are exactly this wave's rows); in-order LDS pipe, no barrier needed.
  {
    const int b = bh >> 4, h = bh & 15;
    int r = tid;
    int rs2 = r & 7;
    size_t gbase = ((size_t)(b * 2048 + q0 + r)) * 1024 + h * 64;
    const unsigned short* lsrc = ep + r * 64;
#pragma unroll
    for (int j = 0; j < 8; ++j)
      *(ulonglong2*)(ctx + gbase + (size_t)j * 8) =
          *(const ulonglong2*)(lsrc + ((j ^ rs2) << 3));
  }
}

// ---------------- output GEMM: out[8192,1024] = ctx @ Wo^T + bo (fp32 out) ----------------
// XCD-swizzled 1D grid (512): 1 n-tile per XCD -> 0.25 MB B strip L2-resident.
// Only 2 blocks/CU -> little TLP: double-buffer staging with counted vmcnt
// (raw s_barrier, never drain to 0 in-loop) to hide load latency intra-block.
__global__ __launch_bounds__(256) void gemm_out(
    const unsigned short* __restrict__ ctx, const unsigned short* __restrict__ wo,
    const float* __restrict__ bo, float* __restrict__ out) {
  __shared__ __align__(16) unsigned short As[2][128 * 32];   // 16 KB
  __shared__ __align__(16) unsigned short Bs[2][128 * 32];   // 16 KB
  const int bid = blockIdx.x;
  const int n0 = (bid & 7) * 128;
  const int m0 = (bid >> 3) * 128;
  const int tid = threadIdx.x;
  const int wv = tid >> 6, lane = tid & 63, qq = lane >> 4, ln = lane & 15;
  const int wm = wv & 1, wn = wv >> 1;
  const int K = 1024;

  f32x4 acc[4][4];
#pragma unroll
  for (int i = 0; i < 4; ++i)
#pragma unroll
    for (int j = 0; j < 4; ++j) acc[i][j] = f32x4{0.f, 0.f, 0.f, 0.f};

  auto stage = [&](int t, int buf) {               // 4 loads per wave
#pragma unroll
    for (int i = 0; i < 2; ++i) {
      int cc = wv * 2 + i;
      int jp = cc * 64 + lane;
      int row = jp >> 2, cp = jp & 3;
      int c = cp ^ ((row >> 1) & 3);
      async16(ctx + (size_t)(m0 + row) * K + t * 32 + c * 8, As[buf] + cc * 512);
      async16(wo  + (size_t)(n0 + row) * K + t * 32 + c * 8, Bs[buf] + cc * 512);
    }
  };

  stage(0, 0);
  for (int t = 0; t < 32; ++t) {
    const int cur = t & 1;
    if (t < 31) {
      stage(t + 1, cur ^ 1);
      // outstanding: stage(t)[4] + stage(t+1)[4] -> retire stage(t) only
      asm volatile("s_waitcnt vmcnt(4)" ::: "memory");
    } else {
      asm volatile("s_waitcnt vmcnt(0)" ::: "memory");
    }
    __builtin_amdgcn_s_barrier();                  // buf[cur] visible from all waves

    bf16x8 af[4], bf[4];
#pragma unroll
    for (int i = 0; i < 4; ++i) {
      int row = wm * 64 + i * 16 + ln;
      af[i] = *(const bf16x8*)(As[cur] + row * 32 + (qq ^ ((row >> 1) & 3)) * 8);
    }
#pragma unroll
    for (int j = 0; j < 4; ++j) {
      int row = wn * 64 + j * 16 + ln;
      bf[j] = *(const bf16x8*)(Bs[cur] + row * 32 + (qq ^ ((row >> 1) & 3)) * 8);
    }
#pragma unroll
    for (int i = 0; i < 4; ++i)
#pragma unroll
      for (int j = 0; j < 4; ++j)
        acc[i][j] = __builtin_amdgcn_mfma_f32_16x16x32_bf16(af[i], bf[j], acc[i][j], 0, 0, 0);
    __builtin_amdgcn_s_barrier();                  // done reading buf[cur]
  }

#pragma unroll
  for (int j = 0; j < 4; ++j) {
    int n = n0 + wn * 64 + j * 16 + ln;
    float bsv = bo[n];
#pragma unroll
    for (int i = 0; i < 4; ++i) {
#pragma unroll
      for (int r = 0; r < 4; ++r) {
        int m = m0 + wm * 64 + i * 16 + qq * 4 + r;
        out[(size_t)m * 1024 + n] = acc[i][j][r] + bsv;
      }
    }
  }
}

// ---------------- launch ----------------
extern "C" void kernel_launch(void* const* d_in, const int* in_sizes, int n_in,
                              void* d_out, int out_size, void* d_ws, size_t ws_size,
                              hipStream_t stream) {
  const float* x  = (const float*)d_in[0];
  const float* Wq = (const float*)d_in[1];
  const float* bq = (const float*)d_in[2];
  const float* Wk = (const float*)d_in[3];
  const float* bk = (const float*)d_in[4];
  const float* Wv = (const float*)d_in[5];
  const float* bv = (const float*)d_in[6];
  const float* Wo = (const float*)d_in[7];
  const float* bo = (const float*)d_in[8];
  float* out = (float*)d_out;

  char* ws = (char*)d_ws;
  unsigned short* xb   = (unsigned short*)(ws);                      // 16M
  unsigned short* ctxb = (unsigned short*)(ws);                      // reuse
  unsigned short* qb   = (unsigned short*)(ws + ((size_t)16 << 20)); // 16M
  unsigned short* kbuf = (unsigned short*)(ws + ((size_t)32 << 20)); // 16M
  unsigned short* vbuf = (unsigned short*)(ws + ((size_t)48 << 20)); // 16M
  unsigned short* wqkv = (unsigned short*)(ws + ((size_t)64 << 20)); // 6M
  unsigned short* wo   = (unsigned short*)(ws + ((size_t)70 << 20)); // 2M

  cast_all<<<12288, 256, 0, stream>>>(x, Wq, Wk, Wv, Wo, xb, wqkv, wo);

  gemm_qkv<<<1536, 256, 0, stream>>>(xb, wqkv, bq, bk, bv, qb, kbuf, vbuf);
  attn_kernel<<<512, 256, 0, stream>>>(qb, kbuf, vbuf, ctxb);
  gemm_out<<<512, 256, 0, stream>>>(ctxb, wo, bo, out);
}

// Round 6
// 286.524 us; speedup vs baseline: 1.0385x; 1.0025x over previous
//
#include <hip/hip_runtime.h>
#include <hip/hip_bf16.h>
#include <stdint.h>

// ---------------- common types / helpers ----------------
typedef __attribute__((ext_vector_type(8))) short  bf16x8;   // 8 bf16 in 4 VGPRs
typedef __attribute__((ext_vector_type(4))) float  f32x4;
typedef __attribute__((ext_vector_type(4))) unsigned int u32x4;
typedef __attribute__((ext_vector_type(2))) unsigned int u32x2;

#define LOG2E 1.4426950408889634f

__device__ __forceinline__ unsigned short f2bf(float f) {
  unsigned int u = __builtin_bit_cast(unsigned int, f);
  u += 0x7fffu + ((u >> 16) & 1u);          // round-to-nearest-even
  return (unsigned short)(u >> 16);
}

// packed 2xfp32 -> 2xbf16 (v_cvt_pk_bf16_f32 on gfx950), returned as u32
__device__ __forceinline__ unsigned int pk2(float a, float b) {
  __hip_bfloat162 h = __float22bfloat162_rn(make_float2(a, b));
  unsigned int u;
  __builtin_memcpy(&u, &h, 4);
  return u;
}

// async global->LDS, 16B per lane. LDS dest = wave-uniform base + lane*16.
__device__ __forceinline__ void async16(const void* g, void* l) {
  __builtin_amdgcn_global_load_lds(
      (const __attribute__((address_space(1))) unsigned int*)g,
      (__attribute__((address_space(3))) unsigned int*)l,
      16, 0, 0);
}

// ---------------- cast all fp32 inputs -> bf16 in one launch ----------------
// x: 2,097,152 float4; weights: 4 x 262,144 float4. Grid 12288 x 256.
__global__ __launch_bounds__(256) void cast_all(
    const float* __restrict__ x,
    const float* __restrict__ Wq, const float* __restrict__ Wk,
    const float* __restrict__ Wv, const float* __restrict__ Wo,
    unsigned short* __restrict__ xb, unsigned short* __restrict__ wqkv,
    unsigned short* __restrict__ wo) {
  int i = blockIdx.x * 256 + threadIdx.x;
  const float* src;
  unsigned short* dst;
  int off;
  if (i < 2097152) {
    src = x; dst = xb; off = i;
  } else {
    int j = i - 2097152;
    int seg = j >> 18; off = j & 262143;
    src = (seg == 0) ? Wq : (seg == 1) ? Wk : (seg == 2) ? Wv : Wo;
    dst = (seg < 3) ? (wqkv + (size_t)seg * 1048576) : wo;
  }
  float4 f = ((const float4*)src)[off];
  uint2 o;
  o.x = pk2(f.x, f.y);
  o.y = pk2(f.z, f.w);
  ((uint2*)dst)[off] = o;
}

// ---------------- QKV GEMM: C[8192,3072] = x_bf16 @ Wqkv^T + bias ----------------
// XCD-swizzled 1D grid (1536): each XCD owns 3 n-tiles -> its 0.75 MB B strip
// stays L2-resident across all 64 m-tiles. Epilogue stages each wave's 64x64 C
// quadrant in private LDS (stride 72), then coalesced 16B stores.
// Q is scaled by 0.125*log2(e): attn then uses exp2() directly.
__global__ __launch_bounds__(256) void gemm_qkv(
    const unsigned short* __restrict__ xb, const unsigned short* __restrict__ wqkv,
    const float* __restrict__ bq, const float* __restrict__ bk, const float* __restrict__ bv,
    unsigned short* __restrict__ qb, unsigned short* __restrict__ kb,
    unsigned short* __restrict__ vb) {
  __shared__ __align__(16) unsigned short As[128 * 32];
  __shared__ __align__(16) unsigned short Bs[128 * 32];
  __shared__ __align__(16) unsigned short epi[4][64 * 72];   // 36 KB, wave-private
  const int bid = blockIdx.x;
  const int xcd = bid & 7, idx = bid >> 3;       // bid%8 ~ XCD round-robin heuristic
  const int nt = xcd * 3 + (idx % 3);            // 24 n-tiles: 3 per XCD
  const int mt = idx / 3;                        // 64 m-tiles
  const int m0 = mt * 128, n0 = nt * 128;
  const int tid = threadIdx.x;
  const int wv = tid >> 6, lane = tid & 63, qq = lane >> 4, ln = lane & 15;
  const int wm = wv & 1, wn = wv >> 1;
  const int K = 1024;

  f32x4 acc[4][4];
#pragma unroll
  for (int i = 0; i < 4; ++i)
#pragma unroll
    for (int j = 0; j < 4; ++j) acc[i][j] = f32x4{0.f, 0.f, 0.f, 0.f};

  for (int k0 = 0; k0 < K; k0 += 32) {
#pragma unroll
    for (int i = 0; i < 2; ++i) {
      int cc = wv * 2 + i;
      int jp = cc * 64 + lane;
      int row = jp >> 2, cp = jp & 3;
      int c = cp ^ ((row >> 1) & 3);
      async16(xb   + (size_t)(m0 + row) * K + k0 + c * 8, As + cc * 512);
      async16(wqkv + (size_t)(n0 + row) * K + k0 + c * 8, Bs + cc * 512);
    }
    __syncthreads();
    bf16x8 af[4], bf[4];
#pragma unroll
    for (int i = 0; i < 4; ++i) {
      int row = wm * 64 + i * 16 + ln;
      af[i] = *(const bf16x8*)(As + row * 32 + (qq ^ ((row >> 1) & 3)) * 8);
    }
#pragma unroll
    for (int j = 0; j < 4; ++j) {
      int row = wn * 64 + j * 16 + ln;
      bf[j] = *(const bf16x8*)(Bs + row * 32 + (qq ^ ((row >> 1) & 3)) * 8);
    }
#pragma unroll
    for (int i = 0; i < 4; ++i)
#pragma unroll
      for (int j = 0; j < 4; ++j)
        acc[i][j] = __builtin_amdgcn_mfma_f32_16x16x32_bf16(af[i], bf[j], acc[i][j], 0, 0, 0);
    __syncthreads();
  }

  const int nblk = n0 >> 10;                           // 0=Q 1=K 2=V (block-uniform)
  const float* bias = (nblk == 0) ? bq : (nblk == 1) ? bk : bv;
  // Q: fold 1/sqrt(64) AND log2(e) so attention can use exp2 directly
  const float scale = (nblk == 0) ? (0.125f * LOG2E) : 1.0f;
  unsigned short* buf = epi[wv];
  const int ncol0 = (n0 & 1023) + wn * 64;             // multiple of 64
  const int head  = ncol0 >> 6;
  const int mbase = m0 + wm * 64;
  const int b     = mbase >> 11, sbase = mbase & 2047;
  unsigned short* dst = (nblk == 0) ? qb : (nblk == 1) ? kb : vb;

  if (nblk != 2) {
    // ---- Q/K: LDS layout [m(s)][n(d)], stride 72 elems ----
#pragma unroll
    for (int j = 0; j < 4; ++j) {
      float bs = bias[ncol0 + j * 16 + ln] * scale;
#pragma unroll
      for (int i = 0; i < 4; ++i)
#pragma unroll
        for (int r = 0; r < 4; ++r)
          buf[(i * 16 + qq * 4 + r) * 72 + j * 16 + ln] = f2bf(acc[i][j][r] * scale + bs);
    }
    unsigned short* gout = dst + (((size_t)(b * 16 + head)) * 2048 + sbase) * 64;
#pragma unroll
    for (int h = 0; h < 2; ++h)
#pragma unroll
      for (int p = 0; p < 4; ++p) {
        int rr = (lane >> 2) + p * 16;
        int c4 = lane & 3;
        ulonglong2 v = *(const ulonglong2*)(buf + rr * 72 + h * 32 + c4 * 8);
        *(ulonglong2*)(gout + (size_t)rr * 64 + h * 32 + c4 * 8) = v;
      }
  } else {
    // ---- V: LDS layout [n(d)][m(s)], stride 72 elems; packed b64 writes ----
#pragma unroll
    for (int j = 0; j < 4; ++j) {
      float bs = bias[ncol0 + j * 16 + ln];
#pragma unroll
      for (int i = 0; i < 4; ++i) {
        uint2 pk;
        pk.x = pk2(acc[i][j][0] + bs, acc[i][j][1] + bs);
        pk.y = pk2(acc[i][j][2] + bs, acc[i][j][3] + bs);
        *(uint2*)(buf + (j * 16 + ln) * 72 + i * 16 + qq * 4) = pk;
      }
    }
    unsigned short* gout = dst + ((size_t)(b * 16 + head)) * 64 * 2048 + sbase;
#pragma unroll
    for (int p = 0; p < 8; ++p) {
      int dr = (lane >> 3) + p * 8;
      int c8 = lane & 7;
      ulonglong2 v = *(const ulonglong2*)(buf + dr * 72 + c8 * 8);
      *(ulonglong2*)(gout + (size_t)dr * 2048 + c8 * 8) = v;
    }
  }
}

// ---------------- flash attention: pipelined tile body (MFMA||VALU overlap) ----
// Same verified structure/math as round 5 (rb=4, dbuf K+V, asm fences, raw
// barriers, in-reg P via permlane, fp32 denominator). ONE change: the tile
// body is software-pipelined across rb-chunks with NO setprio fences:
//   QK(0); QK(1)||SM(0); QK(2)||SM(1)||PV(0); QK(3)||SM(2)||PV(1);
//   SM(3)||PV(2); PV(3)
// Rationale (r0/r2/r5 post-mortems): wall time ~= MFMA-cycles + VALU-cycles
// (sum, not max; MfmaUtil ~30% + VALUBusy ~52% in every schedule) because the
// serial QK->softmax->PV chain + setprio scheduling fences kept the matrix
// pipe idle during softmax. Interleaving independent rb work lets the wave
// issue MFMAs that execute asynchronously under the softmax VALU/trans ops.
__global__ __launch_bounds__(256, 2) void attn_kernel(
    const unsigned short* __restrict__ qb, const unsigned short* __restrict__ kb,
    const unsigned short* __restrict__ vb, unsigned short* __restrict__ ctx) {
  // unified 32 KB LDS: [0..4095]=K buf0, [4096..8191]=K buf1,
  // [8192..12287]=V^T buf0, [12288..16383]=V^T buf1; epilogue reuses all.
  __shared__ __align__(16) unsigned short sh[16384];
  const int bid = blockIdx.x;
  const int xcd = bid & 7, idx = bid >> 3;       // 64 blocks per XCD
  const int bh = xcd * 8 + (idx >> 3);           // 8 heads per XCD (KV L2-resident)
  const int q0 = (idx & 7) * 256;                // 8 q-tiles of 256 rows
  const int tid = threadIdx.x;
  const int wv = tid >> 6, lane = tid & 63, qq = lane >> 4, ln = lane & 15;

  // Q as B-fragments: B[k=d][n=qrow]; 64 rows per wave (rb=0..3)
  bf16x8 qf[4][2];
  {
    const unsigned short* qbase = qb + ((size_t)bh * 2048 + q0 + wv * 64) * 64;
#pragma unroll
    for (int rb = 0; rb < 4; ++rb)
#pragma unroll
      for (int kq = 0; kq < 2; ++kq)
        qf[rb][kq] = *(const bf16x8*)(qbase + (rb * 16 + ln) * 64 + kq * 32 + qq * 8);
  }

  // O^T accumulators: D[m=d (nt)][n=qrow (rb)]; lane: qrow=ln, d=qq*4+r
  f32x4 o_acc[4][4];
  float l_i[4] = {0.f, 0.f, 0.f, 0.f};
#pragma unroll
  for (int rb = 0; rb < 4; ++rb)
#pragma unroll
    for (int nt = 0; nt < 4; ++nt) o_acc[rb][nt] = f32x4{0.f, 0.f, 0.f, 0.f};
  const f32x4 z4 = f32x4{0.f, 0.f, 0.f, 0.f};

  const unsigned short* kgbase = kb + (size_t)bh * 2048 * 64;
  const unsigned short* vgbase = vb + (size_t)bh * 64 * 2048;
  const int cc0 = wv * 2;                        // this wave's 2 staging chunks

  // stage one 64x64 K tile + one 64x64 V^T tile (4 global_load_lds per wave)
  auto stageKV = [&](int kt, int buf) {
#pragma unroll
    for (int i = 0; i < 2; ++i) {
      int jp = (cc0 + i) * 64 + lane;            // 0..511
      int row = jp >> 3, c = (jp & 7) ^ (row & 7); // pre-swizzled global source
      async16(kgbase + (size_t)(kt * 64 + row) * 64 + c * 8,
              sh + buf * 4096 + (cc0 + i) * 512);
      async16(vgbase + (size_t)row * 2048 + kt * 64 + c * 8,
              sh + 8192 + buf * 4096 + (cc0 + i) * 512);
    }
  };

  stageKV(0, 0);
  asm volatile("s_waitcnt vmcnt(0)" ::: "memory");
  __builtin_amdgcn_s_barrier();

  for (int kt = 0; kt < 32; ++kt) {
    const int cur = kt & 1;
    const unsigned short* kcur = sh + cur * 4096;
    const unsigned short* vcur = sh + 8192 + cur * 4096;
    // prefetch next tile into the buffer all waves finished before last barrier
    if (kt < 31) stageKV(kt + 1, cur ^ 1);

    // ---- all K and V fragments loaded once (16 ds_read_b128) ----
    bf16x8 kf[4][2];
#pragma unroll
    for (int ct = 0; ct < 4; ++ct) {
      int row = ct * 16 + ln;
      kf[ct][0] = *(const bf16x8*)(kcur + row * 64 + ((0 + qq) ^ (row & 7)) * 8);
      kf[ct][1] = *(const bf16x8*)(kcur + row * 64 + ((4 + qq) ^ (row & 7)) * 8);
    }
    bf16x8 vf[2][4];
#pragma unroll
    for (int kk = 0; kk < 2; ++kk)
#pragma unroll
      for (int nt = 0; nt < 4; ++nt) {
        int row = nt * 16 + ln;
        vf[kk][nt] = *(const bf16x8*)(vcur + row * 64 + ((kk * 4 + qq) ^ (row & 7)) * 8);
      }

    // ---- pipeline helpers (all indices compile-time after inlining) ----
    auto QK = [&](const bf16x8& q0f, const bf16x8& q1f, f32x4* s) {
#pragma unroll
      for (int ct = 0; ct < 4; ++ct) {
        s[ct] = __builtin_amdgcn_mfma_f32_16x16x32_bf16(kf[ct][0], q0f, z4, 0, 0, 0);
        s[ct] = __builtin_amdgcn_mfma_f32_16x16x32_bf16(kf[ct][1], q1f, s[ct], 0, 0, 0);
      }
    };
    // s_acc: lane(qq,ln) reg r of ct = P[kpos=ct*16+qq*4+r][qrow]
    // permlane32_swap then permlane16_swap: QK C-layout -> PV B-fragment
    auto SM = [&](float& li, const f32x4* s, bf16x8* pfo) {
      unsigned int W[4][2];
#pragma unroll
      for (int ct = 0; ct < 4; ++ct) {
        float p0 = __builtin_amdgcn_exp2f(s[ct][0]);
        float p1 = __builtin_amdgcn_exp2f(s[ct][1]);
        float p2 = __builtin_amdgcn_exp2f(s[ct][2]);
        float p3 = __builtin_amdgcn_exp2f(s[ct][3]);
        li += (p0 + p1) + (p2 + p3);             // fp32 denominator (r4 lesson)
        W[ct][0] = pk2(p0, p1);
        W[ct][1] = pk2(p2, p3);
      }
#pragma unroll
      for (int kk = 0; kk < 2; ++kk) {
        u32x2 a1 = __builtin_amdgcn_permlane32_swap(W[2 * kk][0], W[2 * kk + 1][0], false, false);
        u32x2 a2 = __builtin_amdgcn_permlane16_swap(a1.x, a1.y, false, false);
        u32x2 b1 = __builtin_amdgcn_permlane32_swap(W[2 * kk][1], W[2 * kk + 1][1], false, false);
        u32x2 b2 = __builtin_amdgcn_permlane16_swap(b1.x, b1.y, false, false);
        u32x4 pw = {a2.x, b2.x, a2.y, b2.y};
        pfo[kk] = __builtin_bit_cast(bf16x8, pw);
      }
    };
    auto PV = [&](f32x4* oa, const bf16x8* pfi) {
#pragma unroll
      for (int kk = 0; kk < 2; ++kk)
#pragma unroll
        for (int nt = 0; nt < 4; ++nt)
          oa[nt] = __builtin_amdgcn_mfma_f32_16x16x32_bf16(vf[kk][nt], pfi[kk], oa[nt], 0, 0, 0);
    };

    // ---- pipelined schedule: MFMA of stage i+1 overlaps VALU of stage i ----
    f32x4 s0[4], s1[4], s2[4], s3[4];
    bf16x8 p0[2], p1[2], p2[2], p3[2];
    QK(qf[0][0], qf[0][1], s0);
    QK(qf[1][0], qf[1][1], s1);  SM(l_i[0], s0, p0);
    QK(qf[2][0], qf[2][1], s2);  SM(l_i[1], s1, p1);  PV(o_acc[0], p0);
    QK(qf[3][0], qf[3][1], s3);  SM(l_i[2], s2, p2);  PV(o_acc[1], p1);
                                 SM(l_i[3], s3, p3);  PV(o_acc[2], p2);
                                                      PV(o_acc[3], p3);

    // own stage(t+1) loads landed (covered by compute); barrier publishes them
    if (kt < 31) asm volatile("s_waitcnt vmcnt(0)" ::: "memory");
    __builtin_amdgcn_s_barrier();
  }

  // finalize row sums (cross-quad), normalize, transpose via reused sh (32 KB)
  unsigned short* ep = sh;                       // 256 rows x 64 cols, swizzled
#pragma unroll
  for (int rb = 0; rb < 4; ++rb) {
    l_i[rb] += __shfl_xor(l_i[rb], 16);
    l_i[rb] += __shfl_xor(l_i[rb], 32);
    float inv = 1.0f / l_i[rb];
    int row = wv * 64 + rb * 16 + ln;
    int rs = row & 7;
#pragma unroll
    for (int nt = 0; nt < 4; ++nt) {
      uint2 pk;
      pk.x = pk2(o_acc[rb][nt][0] * inv, o_acc[rb][nt][1] * inv);
      pk.y = pk2(o_acc[rb][nt][2] * inv, o_acc[rb][nt][3] * inv);
      *(uint2*)(ep + row * 64 + (((nt * 2 + (qq >> 1)) ^ rs) << 3) + ((qq & 1) << 2)) = pk;
    }
  }
  // same-wave transposed read: thread tid reads row tid (rows [wv*64,wv*64+63]
  // are exactly this wave's rows); in-order LDS pipe, no barrier needed.
  {
    const int b = bh >> 4, h = bh & 15;
    int r = tid;
    int rs2 = r & 7;
    size_t gbase = ((size_t)(b * 2048 + q0 + r)) * 1024 + h * 64;
    const unsigned short* lsrc = ep + r * 64;
#pragma unroll
    for (int j = 0; j < 8; ++j)
      *(ulonglong2*)(ctx + gbase + (size_t)j * 8) =
          *(const ulonglong2*)(lsrc + ((j ^ rs2) << 3));
  }
}

// ---------------- output GEMM: out[8192,1024] = ctx @ Wo^T + bo (fp32 out) ----------------
// XCD-swizzled 1D grid (512): 1 n-tile per XCD -> 0.25 MB B strip L2-resident.
// Only 2 blocks/CU -> little TLP: double-buffer staging with counted vmcnt
// (raw s_barrier, never drain to 0 in-loop) to hide load latency intra-block.
__global__ __launch_bounds__(256) void gemm_out(
    const unsigned short* __restrict__ ctx, const unsigned short* __restrict__ wo,
    const float* __restrict__ bo, float* __restrict__ out) {
  __shared__ __align__(16) unsigned short As[2][128 * 32];   // 16 KB
  __shared__ __align__(16) unsigned short Bs[2][128 * 32];   // 16 KB
  const int bid = blockIdx.x;
  const int n0 = (bid & 7) * 128;
  const int m0 = (bid >> 3) * 128;
  const int tid = threadIdx.x;
  const int wv = tid >> 6, lane = tid & 63, qq = lane >> 4, ln = lane & 15;
  const int wm = wv & 1, wn = wv >> 1;
  const int K = 1024;

  f32x4 acc[4][4];
#pragma unroll
  for (int i = 0; i < 4; ++i)
#pragma unroll
    for (int j = 0; j < 4; ++j) acc[i][j] = f32x4{0.f, 0.f, 0.f, 0.f};

  auto stage = [&](int t, int buf) {               // 4 loads per wave
#pragma unroll
    for (int i = 0; i < 2; ++i) {
      int cc = wv * 2 + i;
      int jp = cc * 64 + lane;
      int row = jp >> 2, cp = jp & 3;
      int c = cp ^ ((row >> 1) & 3);
      async16(ctx + (size_t)(m0 + row) * K + t * 32 + c * 8, As[buf] + cc * 512);
      async16(wo  + (size_t)(n0 + row) * K + t * 32 + c * 8, Bs[buf] + cc * 512);
    }
  };

  stage(0, 0);
  for (int t = 0; t < 32; ++t) {
    const int cur = t & 1;
    if (t < 31) {
      stage(t + 1, cur ^ 1);
      // outstanding: stage(t)[4] + stage(t+1)[4] -> retire stage(t) only
      asm volatile("s_waitcnt vmcnt(4)" ::: "memory");
    } else {
      asm volatile("s_waitcnt vmcnt(0)" ::: "memory");
    }
    __builtin_amdgcn_s_barrier();                  // buf[cur] visible from all waves

    bf16x8 af[4], bf[4];
#pragma unroll
    for (int i = 0; i < 4; ++i) {
      int row = wm * 64 + i * 16 + ln;
      af[i] = *(const bf16x8*)(As[cur] + row * 32 + (qq ^ ((row >> 1) & 3)) * 8);
    }
#pragma unroll
    for (int j = 0; j < 4; ++j) {
      int row = wn * 64 + j * 16 + ln;
      bf[j] = *(const bf16x8*)(Bs[cur] + row * 32 + (qq ^ ((row >> 1) & 3)) * 8);
    }
#pragma unroll
    for (int i = 0; i < 4; ++i)
#pragma unroll
      for (int j = 0; j < 4; ++j)
        acc[i][j] = __builtin_amdgcn_mfma_f32_16x16x32_bf16(af[i], bf[j], acc[i][j], 0, 0, 0);
    __builtin_amdgcn_s_barrier();                  // done reading buf[cur]
  }

#pragma unroll
  for (int j = 0; j < 4; ++j) {
    int n = n0 + wn * 64 + j * 16 + ln;
    float bsv = bo[n];
#pragma unroll
    for (int i = 0; i < 4; ++i) {
#pragma unroll
      for (int r = 0; r < 4; ++r) {
        int m = m0 + wm * 64 + i * 16 + qq * 4 + r;
        out[(size_t)m * 1024 + n] = acc[i][j][r] + bsv;
      }
    }
  }
}

// ---------------- launch ----------------
extern "C" void kernel_launch(void* const* d_in, const int* in_sizes, int n_in,
                              void* d_out, int out_size, void* d_ws, size_t ws_size,
                              hipStream_t stream) {
  const float* x  = (const float*)d_in[0];
  const float* Wq = (const float*)d_in[1];
  const float* bq = (const float*)d_in[2];
  const float* Wk = (const float*)d_in[3];
  const float* bk = (const float*)d_in[4];
  const float* Wv = (const float*)d_in[5];
  const float* bv = (const float*)d_in[6];
  const float* Wo = (const float*)d_in[7];
  const float* bo = (const float*)d_in[8];
  float* out = (float*)d_out;

  char* ws = (char*)d_ws;
  unsigned short* xb   = (unsigned short*)(ws);                      // 16M
  unsigned short* ctxb = (unsigned short*)(ws);                      // reuse
  unsigned short* qb   = (unsigned short*)(ws + ((size_t)16 << 20)); // 16M
  unsigned short* kbuf = (unsigned short*)(ws + ((size_t)32 << 20)); // 16M
  unsigned short* vbuf = (unsigned short*)(ws + ((size_t)48 << 20)); // 16M
  unsigned short* wqkv = (unsigned short*)(ws + ((size_t)64 << 20)); // 6M
  unsigned short* wo   = (unsigned short*)(ws + ((size_t)70 << 20)); // 2M

  cast_all<<<12288, 256, 0, stream>>>(x, Wq, Wk, Wv, Wo, xb, wqkv, wo);

  gemm_qkv<<<1536, 256, 0, stream>>>(xb, wqkv, bq, bk, bv, qb, kbuf, vbuf);
  attn_kernel<<<512, 256, 0, stream>>>(qb, kbuf, vbuf, ctxb);
  gemm_out<<<512, 256, 0, stream>>>(ctxb, wo, bo, out);
}

// Round 7
// 281.979 us; speedup vs baseline: 1.0553x; 1.0161x over previous
//
#include <hip/hip_runtime.h>
#include <hip/hip_bf16.h>
#include <stdint.h>

// ---------------- common types / helpers ----------------
typedef __attribute__((ext_vector_type(8))) short  bf16x8;   // 8 bf16 in 4 VGPRs
typedef __attribute__((ext_vector_type(4))) float  f32x4;
typedef __attribute__((ext_vector_type(4))) unsigned int u32x4;
typedef __attribute__((ext_vector_type(2))) unsigned int u32x2;

#define LOG2E 1.4426950408889634f

__device__ __forceinline__ unsigned short f2bf(float f) {
  unsigned int u = __builtin_bit_cast(unsigned int, f);
  u += 0x7fffu + ((u >> 16) & 1u);          // round-to-nearest-even
  return (unsigned short)(u >> 16);
}

// packed 2xfp32 -> 2xbf16 (v_cvt_pk_bf16_f32 on gfx950), returned as u32
__device__ __forceinline__ unsigned int pk2(float a, float b) {
  __hip_bfloat162 h = __float22bfloat162_rn(make_float2(a, b));
  unsigned int u;
  __builtin_memcpy(&u, &h, 4);
  return u;
}

// async global->LDS, 16B per lane. LDS dest = wave-uniform base + lane*16.
__device__ __forceinline__ void async16(const void* g, void* l) {
  __builtin_amdgcn_global_load_lds(
      (const __attribute__((address_space(1))) unsigned int*)g,
      (__attribute__((address_space(3))) unsigned int*)l,
      16, 0, 0);
}

// ---------------- cast all fp32 inputs -> bf16 in one launch ----------------
// x: 2,097,152 float4; weights: 4 x 262,144 float4. Grid 12288 x 256.
__global__ __launch_bounds__(256) void cast_all(
    const float* __restrict__ x,
    const float* __restrict__ Wq, const float* __restrict__ Wk,
    const float* __restrict__ Wv, const float* __restrict__ Wo,
    unsigned short* __restrict__ xb, unsigned short* __restrict__ wqkv,
    unsigned short* __restrict__ wo) {
  int i = blockIdx.x * 256 + threadIdx.x;
  const float* src;
  unsigned short* dst;
  int off;
  if (i < 2097152) {
    src = x; dst = xb; off = i;
  } else {
    int j = i - 2097152;
    int seg = j >> 18; off = j & 262143;
    src = (seg == 0) ? Wq : (seg == 1) ? Wk : (seg == 2) ? Wv : Wo;
    dst = (seg < 3) ? (wqkv + (size_t)seg * 1048576) : wo;
  }
  float4 f = ((const float4*)src)[off];
  uint2 o;
  o.x = pk2(f.x, f.y);
  o.y = pk2(f.z, f.w);
  ((uint2*)dst)[off] = o;
}

// ---------------- QKV GEMM: C[8192,3072] = x_bf16 @ Wqkv^T + bias ----------------
// 128x128 tiles, XCD-swizzled grid (1536). Round-7 changes: (a) As/Bs double-
// buffered with counted vmcnt(4) + raw barriers (the r5-verified gemm_out
// pattern); (b) the 36 KB epilogue LDS is overlaid onto the same 32 KB tile
// storage with the stride-64 XOR swizzle (verified attn-epilogue pattern).
// LDS 52 KB -> 32 KB: unlocks 4 blocks/CU if VGPRs permit.
__global__ __launch_bounds__(256) void gemm_qkv(
    const unsigned short* __restrict__ xb, const unsigned short* __restrict__ wqkv,
    const float* __restrict__ bq, const float* __restrict__ bk, const float* __restrict__ bv,
    unsigned short* __restrict__ qb, unsigned short* __restrict__ kb,
    unsigned short* __restrict__ vb) {
  // [0..4095]=A buf0, [4096..8191]=A buf1, [8192..12287]=B buf0,
  // [12288..16383]=B buf1; epilogue: wave wv reuses sh + wv*4096 (64x64).
  __shared__ __align__(16) unsigned short sh[16384];          // 32 KB
  const int bid = blockIdx.x;
  const int xcd = bid & 7, idx = bid >> 3;       // bid%8 ~ XCD round-robin heuristic
  const int nt = xcd * 3 + (idx % 3);            // 24 n-tiles: 3 per XCD
  const int mt = idx / 3;                        // 64 m-tiles
  const int m0 = mt * 128, n0 = nt * 128;
  const int tid = threadIdx.x;
  const int wv = tid >> 6, lane = tid & 63, qq = lane >> 4, ln = lane & 15;
  const int wm = wv & 1, wn = wv >> 1;
  const int K = 1024;

  f32x4 acc[4][4];
#pragma unroll
  for (int i = 0; i < 4; ++i)
#pragma unroll
    for (int j = 0; j < 4; ++j) acc[i][j] = f32x4{0.f, 0.f, 0.f, 0.f};

  auto stage = [&](int k0, int buf) {            // 4 loads per thread
#pragma unroll
    for (int i = 0; i < 2; ++i) {
      int cc = wv * 2 + i;
      int jp = cc * 64 + lane;
      int row = jp >> 2, cp = jp & 3;
      int c = cp ^ ((row >> 1) & 3);
      async16(xb   + (size_t)(m0 + row) * K + k0 + c * 8, sh + buf * 4096 + cc * 512);
      async16(wqkv + (size_t)(n0 + row) * K + k0 + c * 8, sh + 8192 + buf * 4096 + cc * 512);
    }
  };

  stage(0, 0);
  for (int t = 0; t < 32; ++t) {
    const int cur = t & 1;
    if (t < 31) {
      stage((t + 1) * 32, cur ^ 1);
      asm volatile("s_waitcnt vmcnt(4)" ::: "memory");   // retire stage(t) only
    } else {
      asm volatile("s_waitcnt vmcnt(0)" ::: "memory");
    }
    __builtin_amdgcn_s_barrier();                // buf[cur] visible to all waves

    const unsigned short* Asb = sh + cur * 4096;
    const unsigned short* Bsb = sh + 8192 + cur * 4096;
    bf16x8 af[4], bf[4];
#pragma unroll
    for (int i = 0; i < 4; ++i) {
      int row = wm * 64 + i * 16 + ln;
      af[i] = *(const bf16x8*)(Asb + row * 32 + (qq ^ ((row >> 1) & 3)) * 8);
    }
#pragma unroll
    for (int j = 0; j < 4; ++j) {
      int row = wn * 64 + j * 16 + ln;
      bf[j] = *(const bf16x8*)(Bsb + row * 32 + (qq ^ ((row >> 1) & 3)) * 8);
    }
#pragma unroll
    for (int i = 0; i < 4; ++i)
#pragma unroll
      for (int j = 0; j < 4; ++j)
        acc[i][j] = __builtin_amdgcn_mfma_f32_16x16x32_bf16(af[i], bf[j], acc[i][j], 0, 0, 0);
    __builtin_amdgcn_s_barrier();                // done reading buf[cur]
  }
  // after final barrier: all waves done with tile LDS -> safe to overlay epi

  const int nblk = n0 >> 10;                           // 0=Q 1=K 2=V (block-uniform)
  const float* bias = (nblk == 0) ? bq : (nblk == 1) ? bk : bv;
  // Q: fold 1/sqrt(64) AND log2(e) so attention can use exp2 directly
  const float scale = (nblk == 0) ? (0.125f * LOG2E) : 1.0f;
  unsigned short* ep = sh + wv * 4096;                 // 64 rows x 64 cols, swizzled
  const int ncol0 = (n0 & 1023) + wn * 64;             // multiple of 64
  const int head  = ncol0 >> 6;
  const int mbase = m0 + wm * 64;
  const int b     = mbase >> 11, sbase = mbase & 2047;
  unsigned short* dst = (nblk == 0) ? qb : (nblk == 1) ? kb : vb;

  if (nblk != 2) {
    // ---- Q/K: LDS layout [m(s)][n(d)], stride 64, XOR-swizzled chunks ----
#pragma unroll
    for (int j = 0; j < 4; ++j) {
      float bs = bias[ncol0 + j * 16 + ln] * scale;
      int csl = j * 2 + (ln >> 3), c7 = ln & 7;        // logical chunk, sub-offset
#pragma unroll
      for (int i = 0; i < 4; ++i)
#pragma unroll
        for (int r = 0; r < 4; ++r) {
          int row = i * 16 + qq * 4 + r;
          ep[row * 64 + ((csl ^ (row & 7)) << 3) + c7] = f2bf(acc[i][j][r] * scale + bs);
        }
    }
    unsigned short* gout = dst + (((size_t)(b * 16 + head)) * 2048 + sbase) * 64;
#pragma unroll
    for (int h = 0; h < 2; ++h)
#pragma unroll
      for (int p = 0; p < 4; ++p) {
        int rr = (lane >> 2) + p * 16;
        int c4 = lane & 3;
        ulonglong2 v = *(const ulonglong2*)(ep + rr * 64 + (((h * 4 + c4) ^ (rr & 7)) << 3));
        *(ulonglong2*)(gout + (size_t)rr * 64 + h * 32 + c4 * 8) = v;
      }
  } else {
    // ---- V: LDS layout [n(d)][m(s)], stride 64, XOR-swizzled; b64 writes ----
#pragma unroll
    for (int j = 0; j < 4; ++j) {
      float bs = bias[ncol0 + j * 16 + ln];
      int row = j * 16 + ln;                           // d-row
      int rs = row & 7;
#pragma unroll
      for (int i = 0; i < 4; ++i) {
        uint2 pk;
        pk.x = pk2(acc[i][j][0] + bs, acc[i][j][1] + bs);
        pk.y = pk2(acc[i][j][2] + bs, acc[i][j][3] + bs);
        int slot = (i * 2 + (qq >> 1)) ^ rs;
        *(uint2*)(ep + row * 64 + (slot << 3) + ((qq & 1) << 2)) = pk;
      }
    }
    unsigned short* gout = dst + ((size_t)(b * 16 + head)) * 64 * 2048 + sbase;
#pragma unroll
    for (int p = 0; p < 8; ++p) {
      int dr = (lane >> 3) + p * 8;
      int c8 = lane & 7;
      ulonglong2 v = *(const ulonglong2*)(ep + dr * 64 + ((c8 ^ (dr & 7)) << 3));
      *(ulonglong2*)(gout + (size_t)dr * 2048 + c8 * 8) = v;
    }
  }
}

// ---------------- flash attention: r6 version, unchanged (92.9 us, verified) ----
__global__ __launch_bounds__(256, 2) void attn_kernel(
    const unsigned short* __restrict__ qb, const unsigned short* __restrict__ kb,
    const unsigned short* __restrict__ vb, unsigned short* __restrict__ ctx) {
  __shared__ __align__(16) unsigned short sh[16384];
  const int bid = blockIdx.x;
  const int xcd = bid & 7, idx = bid >> 3;       // 64 blocks per XCD
  const int bh = xcd * 8 + (idx >> 3);           // 8 heads per XCD (KV L2-resident)
  const int q0 = (idx & 7) * 256;                // 8 q-tiles of 256 rows
  const int tid = threadIdx.x;
  const int wv = tid >> 6, lane = tid & 63, qq = lane >> 4, ln = lane & 15;

  bf16x8 qf[4][2];
  {
    const unsigned short* qbase = qb + ((size_t)bh * 2048 + q0 + wv * 64) * 64;
#pragma unroll
    for (int rb = 0; rb < 4; ++rb)
#pragma unroll
      for (int kq = 0; kq < 2; ++kq)
        qf[rb][kq] = *(const bf16x8*)(qbase + (rb * 16 + ln) * 64 + kq * 32 + qq * 8);
  }

  f32x4 o_acc[4][4];
  float l_i[4] = {0.f, 0.f, 0.f, 0.f};
#pragma unroll
  for (int rb = 0; rb < 4; ++rb)
#pragma unroll
    for (int nt = 0; nt < 4; ++nt) o_acc[rb][nt] = f32x4{0.f, 0.f, 0.f, 0.f};
  const f32x4 z4 = f32x4{0.f, 0.f, 0.f, 0.f};

  const unsigned short* kgbase = kb + (size_t)bh * 2048 * 64;
  const unsigned short* vgbase = vb + (size_t)bh * 64 * 2048;
  const int cc0 = wv * 2;

  auto stageKV = [&](int kt, int buf) {
#pragma unroll
    for (int i = 0; i < 2; ++i) {
      int jp = (cc0 + i) * 64 + lane;
      int row = jp >> 3, c = (jp & 7) ^ (row & 7);
      async16(kgbase + (size_t)(kt * 64 + row) * 64 + c * 8,
              sh + buf * 4096 + (cc0 + i) * 512);
      async16(vgbase + (size_t)row * 2048 + kt * 64 + c * 8,
              sh + 8192 + buf * 4096 + (cc0 + i) * 512);
    }
  };

  stageKV(0, 0);
  asm volatile("s_waitcnt vmcnt(0)" ::: "memory");
  __builtin_amdgcn_s_barrier();

  for (int kt = 0; kt < 32; ++kt) {
    const int cur = kt & 1;
    const unsigned short* kcur = sh + cur * 4096;
    const unsigned short* vcur = sh + 8192 + cur * 4096;
    if (kt < 31) stageKV(kt + 1, cur ^ 1);

    bf16x8 kf[4][2];
#pragma unroll
    for (int ct = 0; ct < 4; ++ct) {
      int row = ct * 16 + ln;
      kf[ct][0] = *(const bf16x8*)(kcur + row * 64 + ((0 + qq) ^ (row & 7)) * 8);
      kf[ct][1] = *(const bf16x8*)(kcur + row * 64 + ((4 + qq) ^ (row & 7)) * 8);
    }
    bf16x8 vf[2][4];
#pragma unroll
    for (int kk = 0; kk < 2; ++kk)
#pragma unroll
      for (int nt = 0; nt < 4; ++nt) {
        int row = nt * 16 + ln;
        vf[kk][nt] = *(const bf16x8*)(vcur + row * 64 + ((kk * 4 + qq) ^ (row & 7)) * 8);
      }

    auto QK = [&](const bf16x8& q0f, const bf16x8& q1f, f32x4* s) {
#pragma unroll
      for (int ct = 0; ct < 4; ++ct) {
        s[ct] = __builtin_amdgcn_mfma_f32_16x16x32_bf16(kf[ct][0], q0f, z4, 0, 0, 0);
        s[ct] = __builtin_amdgcn_mfma_f32_16x16x32_bf16(kf[ct][1], q1f, s[ct], 0, 0, 0);
      }
    };
    auto SM = [&](float& li, const f32x4* s, bf16x8* pfo) {
      unsigned int W[4][2];
#pragma unroll
      for (int ct = 0; ct < 4; ++ct) {
        float p0 = __builtin_amdgcn_exp2f(s[ct][0]);
        float p1 = __builtin_amdgcn_exp2f(s[ct][1]);
        float p2 = __builtin_amdgcn_exp2f(s[ct][2]);
        float p3 = __builtin_amdgcn_exp2f(s[ct][3]);
        li += (p0 + p1) + (p2 + p3);
        W[ct][0] = pk2(p0, p1);
        W[ct][1] = pk2(p2, p3);
      }
#pragma unroll
      for (int kk = 0; kk < 2; ++kk) {
        u32x2 a1 = __builtin_amdgcn_permlane32_swap(W[2 * kk][0], W[2 * kk + 1][0], false, false);
        u32x2 a2 = __builtin_amdgcn_permlane16_swap(a1.x, a1.y, false, false);
        u32x2 b1 = __builtin_amdgcn_permlane32_swap(W[2 * kk][1], W[2 * kk + 1][1], false, false);
        u32x2 b2 = __builtin_amdgcn_permlane16_swap(b1.x, b1.y, false, false);
        u32x4 pw = {a2.x, b2.x, a2.y, b2.y};
        pfo[kk] = __builtin_bit_cast(bf16x8, pw);
      }
    };
    auto PV = [&](f32x4* oa, const bf16x8* pfi) {
#pragma unroll
      for (int kk = 0; kk < 2; ++kk)
#pragma unroll
        for (int nt = 0; nt < 4; ++nt)
          oa[nt] = __builtin_amdgcn_mfma_f32_16x16x32_bf16(vf[kk][nt], pfi[kk], oa[nt], 0, 0, 0);
    };

    f32x4 s0[4], s1[4], s2[4], s3[4];
    bf16x8 p0[2], p1[2], p2[2], p3[2];
    QK(qf[0][0], qf[0][1], s0);
    QK(qf[1][0], qf[1][1], s1);  SM(l_i[0], s0, p0);
    QK(qf[2][0], qf[2][1], s2);  SM(l_i[1], s1, p1);  PV(o_acc[0], p0);
    QK(qf[3][0], qf[3][1], s3);  SM(l_i[2], s2, p2);  PV(o_acc[1], p1);
                                 SM(l_i[3], s3, p3);  PV(o_acc[2], p2);
                                                      PV(o_acc[3], p3);

    if (kt < 31) asm volatile("s_waitcnt vmcnt(0)" ::: "memory");
    __builtin_amdgcn_s_barrier();
  }

  unsigned short* ep = sh;
#pragma unroll
  for (int rb = 0; rb < 4; ++rb) {
    l_i[rb] += __shfl_xor(l_i[rb], 16);
    l_i[rb] += __shfl_xor(l_i[rb], 32);
    float inv = 1.0f / l_i[rb];
    int row = wv * 64 + rb * 16 + ln;
    int rs = row & 7;
#pragma unroll
    for (int nt = 0; nt < 4; ++nt) {
      uint2 pk;
      pk.x = pk2(o_acc[rb][nt][0] * inv, o_acc[rb][nt][1] * inv);
      pk.y = pk2(o_acc[rb][nt][2] * inv, o_acc[rb][nt][3] * inv);
      *(uint2*)(ep + row * 64 + (((nt * 2 + (qq >> 1)) ^ rs) << 3) + ((qq & 1) << 2)) = pk;
    }
  }
  {
    const int b = bh >> 4, h = bh & 15;
    int r = tid;
    int rs2 = r & 7;
    size_t gbase = ((size_t)(b * 2048 + q0 + r)) * 1024 + h * 64;
    const unsigned short* lsrc = ep + r * 64;
#pragma unroll
    for (int j = 0; j < 8; ++j)
      *(ulonglong2*)(ctx + gbase + (size_t)j * 8) =
          *(const ulonglong2*)(lsrc + ((j ^ rs2) << 3));
  }
}

// ---------------- output GEMM: out[8192,1024] = ctx @ Wo^T + bo (fp32 out) ----------------
// Round-7 retile: 64x128 tiles -> grid 1024 (4 blocks/CU, was 2). 4 waves
// split N (each 64m x 32n, acc[4][2]). LDS 24 KB dbuf, counted vmcnt(3).
// XCD-swizzled: n0 = (bid&7)*128 -> per-XCD 0.25 MB B strip L2-resident.
__global__ __launch_bounds__(256, 4) void gemm_out(
    const unsigned short* __restrict__ ctx, const unsigned short* __restrict__ wo,
    const float* __restrict__ bo, float* __restrict__ out) {
  __shared__ __align__(16) unsigned short Asd[2][64 * 32];    // 8 KB
  __shared__ __align__(16) unsigned short Bsd[2][128 * 32];   // 16 KB
  const int bid = blockIdx.x;
  const int n0 = (bid & 7) * 128;
  const int m0 = (bid >> 3) * 64;                // 128 m-tiles of 64 rows
  const int tid = threadIdx.x;
  const int wv = tid >> 6, lane = tid & 63, qq = lane >> 4, ln = lane & 15;
  const int K = 1024;

  f32x4 acc[4][2];
#pragma unroll
  for (int i = 0; i < 4; ++i)
#pragma unroll
    for (int j = 0; j < 2; ++j) acc[i][j] = f32x4{0.f, 0.f, 0.f, 0.f};

  auto stage = [&](int t, int buf) {             // 3 loads per thread
    {
      int jp = wv * 64 + lane;                   // A: 4 chunk-groups, one per wave
      int row = jp >> 2, cp = jp & 3;
      int c = cp ^ ((row >> 1) & 3);
      async16(ctx + (size_t)(m0 + row) * K + t * 32 + c * 8, Asd[buf] + wv * 512);
    }
#pragma unroll
    for (int i = 0; i < 2; ++i) {                // B: 8 chunk-groups, two per wave
      int cc = wv * 2 + i;
      int jp = cc * 64 + lane;
      int row = jp >> 2, cp = jp & 3;
      int c = cp ^ ((row >> 1) & 3);
      async16(wo + (size_t)(n0 + row) * K + t * 32 + c * 8, Bsd[buf] + cc * 512);
    }
  };

  stage(0, 0);
  for (int t = 0; t < 32; ++t) {
    const int cur = t & 1;
    if (t < 31) {
      stage(t + 1, cur ^ 1);
      asm volatile("s_waitcnt vmcnt(3)" ::: "memory");   // retire stage(t) only
    } else {
      asm volatile("s_waitcnt vmcnt(0)" ::: "memory");
    }
    __builtin_amdgcn_s_barrier();                // buf[cur] visible to all waves

    bf16x8 af[4], bf[2];
#pragma unroll
    for (int i = 0; i < 4; ++i) {
      int row = i * 16 + ln;
      af[i] = *(const bf16x8*)(Asd[cur] + row * 32 + (qq ^ ((row >> 1) & 3)) * 8);
    }
#pragma unroll
    for (int j = 0; j < 2; ++j) {
      int row = wv * 32 + j * 16 + ln;
      bf[j] = *(const bf16x8*)(Bsd[cur] + row * 32 + (qq ^ ((row >> 1) & 3)) * 8);
    }
#pragma unroll
    for (int i = 0; i < 4; ++i)
#pragma unroll
      for (int j = 0; j < 2; ++j)
        acc[i][j] = __builtin_amdgcn_mfma_f32_16x16x32_bf16(af[i], bf[j], acc[i][j], 0, 0, 0);
    __builtin_amdgcn_s_barrier();                // done reading buf[cur]
  }

#pragma unroll
  for (int j = 0; j < 2; ++j) {
    int n = n0 + wv * 32 + j * 16 + ln;
    float bsv = bo[n];
#pragma unroll
    for (int i = 0; i < 4; ++i) {
#pragma unroll
      for (int r = 0; r < 4; ++r) {
        int m = m0 + i * 16 + qq * 4 + r;
        out[(size_t)m * 1024 + n] = acc[i][j][r] + bsv;
      }
    }
  }
}

// ---------------- launch ----------------
extern "C" void kernel_launch(void* const* d_in, const int* in_sizes, int n_in,
                              void* d_out, int out_size, void* d_ws, size_t ws_size,
                              hipStream_t stream) {
  const float* x  = (const float*)d_in[0];
  const float* Wq = (const float*)d_in[1];
  const float* bq = (const float*)d_in[2];
  const float* Wk = (const float*)d_in[3];
  const float* bk = (const float*)d_in[4];
  const float* Wv = (const float*)d_in[5];
  const float* bv = (const float*)d_in[6];
  const float* Wo = (const float*)d_in[7];
  const float* bo = (const float*)d_in[8];
  float* out = (float*)d_out;

  char* ws = (char*)d_ws;
  unsigned short* xb   = (unsigned short*)(ws);                      // 16M
  unsigned short* ctxb = (unsigned short*)(ws);                      // reuse
  unsigned short* qb   = (unsigned short*)(ws + ((size_t)16 << 20)); // 16M
  unsigned short* kbuf = (unsigned short*)(ws + ((size_t)32 << 20)); // 16M
  unsigned short* vbuf = (unsigned short*)(ws + ((size_t)48 << 20)); // 16M
  unsigned short* wqkv = (unsigned short*)(ws + ((size_t)64 << 20)); // 6M
  unsigned short* wo   = (unsigned short*)(ws + ((size_t)70 << 20)); // 2M

  cast_all<<<12288, 256, 0, stream>>>(x, Wq, Wk, Wv, Wo, xb, wqkv, wo);

  gemm_qkv<<<1536, 256, 0, stream>>>(xb, wqkv, bq, bk, bv, qb, kbuf, vbuf);
  attn_kernel<<<512, 256, 0, stream>>>(qb, kbuf, vbuf, ctxb);
  gemm_out<<<1024, 256, 0, stream>>>(ctxb, wo, bo, out);
}